// Round 7
// baseline (30.199 us; speedup 1.0000x reference)
//
#include <hip/hip_runtime.h>

// SymPBC feature kernel for MI355X (v6: 1-wave blocks, w-per-lane,
// wave-uniform (m,n) -> conflict-free LDS, register F-row + small obuf
// transpose for coalesced stores).
//
// Math (M=2 dual-pol collapses _triple's pol-swap into a sum over q):
//   B1 = sum_q E[w-n,q]*conj(E[w-m-n,q]);  B2 = sum_q E[w+n,q]*conj(E[w+m+n,q])
//   T1[p] = B1*E[w-m,p] + B2*E[w+m,p]
//   B3 = sum_q E[w-m,q]*conj(E[w-m-n,q]);  B4 = sum_q E[w+m,q]*conj(E[w+m+n,q])
//   T2[p] = B3*E[w-n,p] + B4*E[w+n,p]
//   F = w1*T1 + w2*T2;  w1 = 0.5 iff (m==0 && n==0);  w2 = (n > |m|)
// Output: out[b][w][p][s][c] float32, flat = (b*W+w)*472 + p*236 + s*2 + c.

constexpr int W = 16384;
constexpr int WMASK = W - 1;
constexpr int NB = 2;
constexpr int S = 118;
constexpr int HALO = 26;                // max |m+n|
constexpr int TW = 64;                  // w per block == lanes
constexpr int ELD = TW + 2 * HALO;      // 116
constexpr int CH = 16;                  // s per block
constexpr int NCH = (S + CH - 1) / CH;  // 8
constexpr int SUB = 8;                  // s per store sub-chunk

struct C2 { float re, im; };

// s -> (m,n), Python iteration order. Group starts:
// m=-5:0  -4:1  -3:4  -2:10  -1:21  0:46  1:72  2:97  3:108  4:114  5:117
// s is wave-uniform (from blockIdx.z) -> this scalarizes to SALU.
__device__ inline void decode_s(int s, int& m, int& n) {
    const int g = (s>=1)+(s>=4)+(s>=10)+(s>=21)+(s>=46)
                + (s>=72)+(s>=97)+(s>=108)+(s>=114)+(s>=117);
    const int start = (s>=117)?117:(s>=114)?114:(s>=108)?108:(s>=97)?97:
                      (s>=72)?72:(s>=46)?46:(s>=21)?21:(s>=10)?10:
                      (s>=4)?4:(s>=1)?1:0;
    m = g - 5;
    const int am = (m < 0) ? -m : m;
    n = am + (s - start);
}

// bracket(Xa, Xb) = sum_q Xa_q * conj(Xb_q); X = (re0, im0, re1, im1)
__device__ inline C2 bracket(const float4 a, const float4 b) {
    C2 r;
    r.re = a.x*b.x + a.y*b.y + a.z*b.z + a.w*b.w;
    r.im = a.y*b.x - a.x*b.y + a.w*b.z - a.z*b.w;
    return r;
}

__device__ inline float4 compute_f(const float4 Am, const float4 Ap,
                                   const float4 An, const float4 Bn,
                                   const float4 Amn, const float4 Bmn,
                                   const float w1, const float w2) {
    const C2 B1 = bracket(An, Amn);
    const C2 B2 = bracket(Bn, Bmn);
    float r0 = B1.re*Am.x - B1.im*Am.y + B2.re*Ap.x - B2.im*Ap.y;
    float i0 = B1.re*Am.y + B1.im*Am.x + B2.re*Ap.y + B2.im*Ap.x;
    float r1 = B1.re*Am.z - B1.im*Am.w + B2.re*Ap.z - B2.im*Ap.w;
    float i1 = B1.re*Am.w + B1.im*Am.z + B2.re*Ap.w + B2.im*Ap.z;
    r0 *= w1; i0 *= w1; r1 *= w1; i1 *= w1;
    C2 B3 = bracket(Am, Amn);
    C2 B4 = bracket(Ap, Bmn);
    B3.re *= w2; B3.im *= w2; B4.re *= w2; B4.im *= w2;
    r0 += B3.re*An.x - B3.im*An.y + B4.re*Bn.x - B4.im*Bn.y;
    i0 += B3.re*An.y + B3.im*An.x + B4.re*Bn.y + B4.im*Bn.x;
    r1 += B3.re*An.z - B3.im*An.w + B4.re*Bn.z - B4.im*Bn.w;
    i1 += B3.re*An.w + B3.im*An.z + B4.re*Bn.w + B4.im*Bn.z;
    return make_float4(r0, i0, r1, i1);
}

__global__ __launch_bounds__(64) void sympbc_kernel(
    const float* __restrict__ Er, const float* __restrict__ Ei,
    float* __restrict__ out)
{
    __shared__ float4 eld[ELD];
    __shared__ float4 obuf[SUB][TW + 1];   // row stride 65 (== 1 mod 8): min-phase

    const int lane = threadIdx.x;          // one wave per block
    const int b = blockIdx.y;
    const int tile0 = blockIdx.x * TW;
    const int s_lo = blockIdx.z * CH;

    // Stage E window: interleaved complex dual-pol (re0, im0, re1, im1).
    #pragma unroll
    for (int k = 0; k < 2; ++k) {
        const int x = lane + 64 * k;
        if (x < ELD) {
            const int gw = (tile0 - HALO + x) & WMASK;
            const size_t gi = ((size_t)b * W + gw) * 2;
            const float2 r = *reinterpret_cast<const float2*>(Er + gi);
            const float2 i = *reinterpret_cast<const float2*>(Ei + gi);
            eld[x] = make_float4(r.x, i.x, r.y, i.y);
        }
    }
    __syncthreads();

    const int ci = HALO + lane;
    const float4 Eself = eld[ci];

    #pragma unroll
    for (int sc = 0; sc < CH / SUB; ++sc) {
        const int s0 = s_lo + SUB * sc;
        const int cnt = (S - s0 < SUB) ? (S - s0) : SUB;   // 8, 8, ..., 6 (even)
        if (cnt <= 0) break;

        // ---- compute SUB s-values; all offsets wave-uniform -> stride-1 reads
        for (int j = 0; j < SUB; ++j) {
            if (j >= cnt) break;
            const int s = s0 + j;
            int m, n;
            decode_s(s, m, n);
            const int am = (m < 0) ? -m : m;
            const int mn = m + n;
            const float w1 = (m == 0 && n == 0) ? 0.5f : 1.0f;
            const float w2 = (n > am) ? 1.0f : 0.0f;

            const float4 An = eld[ci - n];
            const float4 Bn = eld[ci + n];
            float4 Am, Ap, Amn, Bmn;
            if (m == 0) {              // uniform branch; 26 of 118 s-values
                Am = Eself; Ap = Eself; Amn = An; Bmn = Bn;
            } else {
                Am  = eld[ci - m];  Ap  = eld[ci + m];
                Amn = eld[ci - mn]; Bmn = eld[ci + mn];
            }
            obuf[j][lane] = compute_f(Am, Ap, An, Bn, Amn, Bmn, w1, w2);
        }
        __syncthreads();

        // ---- store: lane -> (w-quarter, s-pair); 64 B contiguous per (w,p)
        const int q  = lane & 3;          // s-pair within sub-chunk
        const int wb = lane >> 2;         // w base 0..15
        if (2 * q < cnt) {
            const size_t ocol = (size_t)(s0 + 2 * q) * 2;
            #pragma unroll
            for (int r = 0; r < 4; ++r) {
                const int w = wb + 16 * r;
                const float4 F0 = obuf[2 * q][w];
                const float4 F1 = obuf[2 * q + 1][w];
                float* o = out + ((size_t)b * W + tile0 + w) * 472 + ocol;
                *reinterpret_cast<float4*>(o) =
                    make_float4(F0.x, F0.y, F1.x, F1.y);      // p=0
                *reinterpret_cast<float4*>(o + 236) =
                    make_float4(F0.z, F0.w, F1.z, F1.w);      // p=1
            }
        }
        __syncthreads();
    }
}

extern "C" void kernel_launch(void* const* d_in, const int* in_sizes, int n_in,
                              void* d_out, int out_size, void* d_ws, size_t ws_size,
                              hipStream_t stream) {
    const float* Er = (const float*)d_in[0];
    const float* Ei = (const float*)d_in[1];
    float* out = (float*)d_out;
    dim3 grid(W / TW, NB, NCH);
    sympbc_kernel<<<grid, dim3(64), 0, stream>>>(Er, Ei, out);
}